// Round 7
// baseline (457.511 us; speedup 1.0000x reference)
//
#include <hip/hip_runtime.h>
#include <stdint.h>

// y[8192,4096] = x[8192,4096] @ W[4096,4096]^T + bias
// W from codebook[4096,8] gathered by indices[2M].
// R11: R10 + double-buffered B fragments (fB0/fB1 register sets).
//      Phase order: [stage] [fC] [fB(next)] [MFMA half0] [fA(next)]
//      [MFMA half1] [vmcnt(4)] [barrier] — no ds_read after half1, so
//      every phase's entry fragments were issued >600 cyc earlier under
//      the previous MFMA window. LDS pipe (~2310 cyc/tile) and matrix
//      pipe (~2480 cyc/tile) now overlap instead of serializing.
//      LDS slots / STAGE schedule / vmcnt FIFO identical to R10.
//      +32 VGPR (5 frag sets); __launch_bounds__(512,2) caps at 256.

#define M_DIM 8192
#define N_DIM 4096
#define K_DIM 4096
#define BM 256
#define BN 256
#define BK 64
#define NT (K_DIM / BK)                       // 64 K-tiles
#define NUM_W_BLOCKS 2097152                  // 4096*4096/8
#define W_WGS (NUM_W_BLOCKS / 256)            // 8192 WGs for W dequant
#define X_WGS ((M_DIM * K_DIM / 4) / 256)     // 32768 WGs, one float4/thread

typedef __attribute__((ext_vector_type(8))) __bf16 bf16x8;
typedef __attribute__((ext_vector_type(4))) float floatx4;
typedef __attribute__((ext_vector_type(2))) unsigned int uintx2;

// fp32 -> bf16 round-to-nearest-even (finite inputs)
__device__ __forceinline__ unsigned int f2bf(float f) {
    unsigned int u = __builtin_bit_cast(unsigned int, f);
    u += 0x7fffu + ((u >> 16) & 1u);
    return u >> 16;
}

// ------------- fused prep: W dequant-gather + x fp32->bf16 -------------
__global__ __launch_bounds__(256) void prep_kernel(
    const float* __restrict__ cb, const int* __restrict__ idx,
    uint4* __restrict__ W, const floatx4* __restrict__ x,
    uintx2* __restrict__ xb) {
    const int wg = blockIdx.x;
    if (wg < W_WGS) {
        const int b = wg * 256 + threadIdx.x;
        const int id = __builtin_nontemporal_load(idx + b);
        const float4* s = (const float4*)(cb + ((size_t)id << 3));
        const float4 a = s[0];
        const float4 c = s[1];
        uint4 o;
        o.x = f2bf(a.x) | (f2bf(a.y) << 16);
        o.y = f2bf(a.z) | (f2bf(a.w) << 16);
        o.z = f2bf(c.x) | (f2bf(c.y) << 16);
        o.w = f2bf(c.z) | (f2bf(c.w) << 16);
        W[b] = o;
    } else {
        const size_t t = (size_t)(wg - W_WGS) * 256 + threadIdx.x;
        const floatx4 a = __builtin_nontemporal_load(x + t);
        uintx2 o;
        o.x = f2bf(a.x) | (f2bf(a.y) << 16);
        o.y = f2bf(a.z) | (f2bf(a.w) << 16);
        xb[t] = o;
    }
}

// ---------------- async global -> LDS, 16B per lane ----------------
__device__ __forceinline__ void async_copy16(const __bf16* g, __bf16* s) {
    __builtin_amdgcn_global_load_lds(
        (const __attribute__((address_space(1))) unsigned int*)(uintptr_t)g,
        (__attribute__((address_space(3))) unsigned int*)(uintptr_t)s,
        16, 0, 0);
}

// Stage one unit = one operand k-half (256 rows x 32 bf16 = 16 KiB):
// 2 global_load_lds per thread (rows 0-127, rows 128-255).
#define STAGE(gsrc, arr, slotElems)                                        \
    do {                                                                   \
        async_copy16((gsrc), (arr) + (slotElems) + wave512);               \
        async_copy16((gsrc) + (size_t)128 * K_DIM,                         \
                     (arr) + (slotElems) + 4096 + wave512);                \
    } while (0)

// ---------------- GEMM: C[M][N] = A[M][K] * B[N][K]^T + bias ----------------
// 512 threads = 8 waves (2M x 4N); wave owns 128x64 output = acc[8][4] f32x4.
// LDS: per operand a 4-slot ring of 16KiB k-half units: slot = (t&1)*2 + kh.
// 2 phases per K-tile. Register sets: (fA0,fB0) carry kh0 frags, (fA1,fB1)
// carry kh1/next-kh0 frags, fC carries the in-phase af1.
//   Phase A (kh0): [STAGE kh1(t+1)] [fC<-af1 kh0] [fB1<-bfr kh1]
//                  [half0: fA0xfB0] [fA1<-af0 kh1] [half1: fCxfB0]
//                  [vmcnt(4)] [barrier]
//   Phase B (kh1): symmetric, prereads kh0(t+1) into fA0/fB0.
// Fences identical to R10: each k-half unit-pair = 4 loads; every phase
// ends vmcnt(4) (drain the older of 2 outstanding unit-pairs); tails 0.
__global__ __launch_bounds__(512, 2) void gemm_bt_kernel(
    const __bf16* __restrict__ A,   // [M][K] bf16
    const __bf16* __restrict__ B,   // [N][K] bf16
    const float* __restrict__ bias, // [N]
    float* __restrict__ C) {        // [M][N] fp32
    __shared__ __align__(16) __bf16 sA[4 * 8192];   // 64 KiB
    __shared__ __align__(16) __bf16 sB[4 * 8192];   // 64 KiB

    const int tid = threadIdx.x;
    const int wave = tid >> 6;
    const int lane = tid & 63;
    const int wr = wave >> 2;            // 0..1  (M half of tile)
    const int wc = wave & 3;             // 0..3  (N quarter of tile)

    // T1: XCD-chunked mapping (verified R6: FETCH 670->197 MB).
    const int flat = blockIdx.x;
    const int xcd = flat & 7;
    const int q = flat >> 3;             // 0..63
    const int half = q >> 5;             // 0..1
    const int sq = q & 31;
    const int m0 = ((xcd & 3) * 8 + half * 4 + (sq & 3)) * BM;
    const int n0 = ((xcd >> 2) * 8 + (sq >> 2)) * BN;

    // staging: thread t covers row = t>>2 (+128 for 2nd half), phys chunk t&3;
    // fetch logical chunk c = p ^ ((row>>1)&3) (involution, invariant +16/+128)
    const int srow = tid >> 2;
    const int schunk = ((tid & 3) ^ ((srow >> 1) & 3)) << 3;
    const __bf16* gA = A + (size_t)(m0 + srow) * K_DIM + schunk;
    const __bf16* gB = B + (size_t)(n0 + srow) * K_DIM + schunk;
    const int wave512 = wave << 9;

    // fragment reads: lane holds X[row = base + fr][k = (lane>>4)*8 + j];
    // physical chunk = (lane>>4) ^ ((fr>>1)&3).
    const int fr = lane & 15;
    const int roff = fr * 32 + (((lane >> 4) ^ ((fr >> 1) & 3)) << 3);
    const int aBase = wr * 4096 + roff;  // wr*128 rows * 32 elems
    const int bBase = wc * 2048 + roff;  // wc*64 rows * 32 elems

    floatx4 acc[8][4] = {};
    bf16x8 fA0[4], fB0[4], fA1[4], fB1[4], fC[4];

    // ---- prologue: kh0(0), kh1(0), kh0(1) staged in FIFO order ----
    STAGE(gA, sA, 0);             // A kh0 t0 -> slot 0
    STAGE(gB, sB, 0);
    STAGE(gA + 32, sA, 8192);     // A kh1 t0 -> slot 1
    STAGE(gB + 32, sB, 8192);
    STAGE(gA + 64, sA, 16384);    // A kh0 t1 -> slot 2
    STAGE(gB + 64, sB, 16384);
    // drain kh0(0)+kh1(0) (8 of 12); kh0(1) stays in flight
    asm volatile("s_waitcnt vmcnt(4)" ::: "memory");
    __builtin_amdgcn_s_barrier();
    // preload entry fragments for phase A(0): af0/bfr of kh0(0)
#pragma unroll
    for (int i = 0; i < 4; ++i)
        fA0[i] = *(const bf16x8*)(sA + aBase + i * 512);
#pragma unroll
    for (int j = 0; j < 4; ++j)
        fB0[j] = *(const bf16x8*)(sB + bBase + j * 512);

    for (int t = 0; t < NT; ++t) {
        const int cs = (t & 1) ? 16384 : 0;   // this tile's kh0 slot (elems)
        const int ns = cs ^ 16384;            // next tile's kh0 slot
        const __bf16* pA0 = sA + cs;          // kh0(t)
        const __bf16* pA1 = sA + cs + 8192;   // kh1(t)
        const __bf16* pB1 = sB + cs + 8192;
        const __bf16* nA0 = sA + ns;          // kh0(t+1)
        const __bf16* nB0 = sB + ns;

        // ===== Phase A: compute kh0(t) [fA0,fB0]; preread kh1(t) =====
        if (t + 1 < NT) {
            STAGE(gA + (size_t)(t + 1) * 64 + 32, sA, ns + 8192);
            STAGE(gB + (size_t)(t + 1) * 64 + 32, sB, ns + 8192);
        }
#pragma unroll
        for (int i = 0; i < 4; ++i)           // af1(kh0): used by half1
            fC[i] = *(const bf16x8*)(pA0 + aBase + 2048 + i * 512);
#pragma unroll
        for (int j = 0; j < 4; ++j)           // bfr(kh1): used next phase
            fB1[j] = *(const bf16x8*)(pB1 + bBase + j * 512);
        __builtin_amdgcn_s_setprio(1);
#pragma unroll
        for (int i = 0; i < 4; ++i)
#pragma unroll
            for (int j = 0; j < 4; ++j)
                acc[i][j] = __builtin_amdgcn_mfma_f32_16x16x32_bf16(
                    fA0[i], fB0[j], acc[i][j], 0, 0, 0);
        __builtin_amdgcn_s_setprio(0);
#pragma unroll
        for (int i = 0; i < 4; ++i)           // af0(kh1): used next phase
            fA1[i] = *(const bf16x8*)(pA1 + aBase + i * 512);
        __builtin_amdgcn_s_setprio(1);
#pragma unroll
        for (int i = 0; i < 4; ++i)
#pragma unroll
            for (int j = 0; j < 4; ++j)
                acc[i + 4][j] = __builtin_amdgcn_mfma_f32_16x16x32_bf16(
                    fC[i], fB0[j], acc[i + 4][j], 0, 0, 0);
        __builtin_amdgcn_s_setprio(0);
        // publish kh0(t+1): outstanding [kh0(t+1)4, kh1(t+1)4] -> 4
        if (t + 1 < NT)
            asm volatile("s_waitcnt vmcnt(4)" ::: "memory");
        else
            asm volatile("s_waitcnt vmcnt(0)" ::: "memory");
        __builtin_amdgcn_s_barrier();

        // ===== Phase B: compute kh1(t) [fA1,fB1]; preread kh0(t+1) =====
        if (t + 2 < NT) {
            STAGE(gA + (size_t)(t + 2) * 64, sA, cs);
            STAGE(gB + (size_t)(t + 2) * 64, sB, cs);
        }
#pragma unroll
        for (int i = 0; i < 4; ++i)           // af1(kh1): used by half1
            fC[i] = *(const bf16x8*)(pA1 + aBase + 2048 + i * 512);
        if (t + 1 < NT) {
#pragma unroll
            for (int j = 0; j < 4; ++j)       // bfr(kh0,t+1): next phase
                fB0[j] = *(const bf16x8*)(nB0 + bBase + j * 512);
        }
        __builtin_amdgcn_s_setprio(1);
#pragma unroll
        for (int i = 0; i < 4; ++i)
#pragma unroll
            for (int j = 0; j < 4; ++j)
                acc[i][j] = __builtin_amdgcn_mfma_f32_16x16x32_bf16(
                    fA1[i], fB1[j], acc[i][j], 0, 0, 0);
        __builtin_amdgcn_s_setprio(0);
        if (t + 1 < NT) {
#pragma unroll
            for (int i = 0; i < 4; ++i)       // af0(kh0,t+1): next phase
                fA0[i] = *(const bf16x8*)(nA0 + aBase + i * 512);
        }
        __builtin_amdgcn_s_setprio(1);
#pragma unroll
        for (int i = 0; i < 4; ++i)
#pragma unroll
            for (int j = 0; j < 4; ++j)
                acc[i + 4][j] = __builtin_amdgcn_mfma_f32_16x16x32_bf16(
                    fC[i], fB1[j], acc[i + 4][j], 0, 0, 0);
        __builtin_amdgcn_s_setprio(0);
        // publish kh1(t+1): outstanding [kh1(t+1)4, kh0(t+2)4] -> 4
        if (t + 2 < NT)
            asm volatile("s_waitcnt vmcnt(4)" ::: "memory");
        else
            asm volatile("s_waitcnt vmcnt(0)" ::: "memory");
        __builtin_amdgcn_s_barrier();
    }

    // Epilogue. C/D layout: col = lane&15, row = (lane>>4)*4 + reg
    const int crow = (lane >> 4) * 4;
    const int ccol = lane & 15;
#pragma unroll
    for (int j = 0; j < 4; ++j) {
        const int n = n0 + wc * 64 + j * 16 + ccol;
        const float bv = bias[n];
#pragma unroll
        for (int i = 0; i < 8; ++i) {
            const int m = m0 + wr * 128 + i * 16 + crow;
            float* cp = C + (size_t)m * N_DIM + n;
#pragma unroll
            for (int r = 0; r < 4; ++r)
                __builtin_nontemporal_store(acc[i][j][r] + bv,
                                            cp + (size_t)r * N_DIM);
        }
    }
}

extern "C" void kernel_launch(void* const* d_in, const int* in_sizes, int n_in,
                              void* d_out, int out_size, void* d_ws, size_t ws_size,
                              hipStream_t stream) {
    const float* x    = (const float*)d_in[0];   // [4,2048,4096] fp32
    const float* cb   = (const float*)d_in[1];   // [4096,8] fp32
    const int*   idx  = (const int*)d_in[2];     // [2M]
    const float* bias = (const float*)d_in[3];   // [4096]
    float* out = (float*)d_out;                  // [4,2048,4096] fp32

    // workspace layout: W_bf16 (32 MB) | x_bf16 (64 MB)
    __bf16* Wb = (__bf16*)d_ws;
    __bf16* Xb = (__bf16*)((char*)d_ws + (size_t)N_DIM * K_DIM * sizeof(__bf16));

    prep_kernel<<<W_WGS + X_WGS, 256, 0, stream>>>(
        cb, idx, (uint4*)Wb, (const floatx4*)x, (uintx2*)Xb);

    dim3 grid(M_DIM / BM * (N_DIM / BN));  // 512 WGs, XCD-chunked in-kernel
    gemm_bt_kernel<<<grid, 512, 0, stream>>>(Xb, Wb, bias, out);
}

// Round 8
// 457.448 us; speedup vs baseline: 1.0001x; 1.0001x over previous
//
#include <hip/hip_runtime.h>
#include <stdint.h>

// y[8192,4096] = x[8192,4096] @ W[4096,4096]^T + bias
// W from codebook[4096,8] gathered by indices[2M].
// R12: R11 + sched_barrier(0) pinning. Diagnosis: compiler sank R11's
//      preread ds_reads to phase end (VGPR unchanged at 128 = the tell),
//      reconstructing the serialized order. Now each phase is
//      [STAGE] [12 ds_reads: fC, fB-next, fA-next] [sched_barrier(0)]
//      [32 MFMA] [vmcnt(4)] [barrier] — reads issue before the MFMA
//      cluster and complete under it. LDS pipe (~1156 cyc/phase) and
//      MFMA pipe (~1242 cyc/phase) overlap instead of serializing.
//      Ring / fences / mapping identical to R11 (clean A/B on scheduling).

#define M_DIM 8192
#define N_DIM 4096
#define K_DIM 4096
#define BM 256
#define BN 256
#define BK 64
#define NT (K_DIM / BK)                       // 64 K-tiles
#define NUM_W_BLOCKS 2097152                  // 4096*4096/8
#define W_WGS (NUM_W_BLOCKS / 256)            // 8192 WGs for W dequant
#define X_WGS ((M_DIM * K_DIM / 4) / 256)     // 32768 WGs, one float4/thread

typedef __attribute__((ext_vector_type(8))) __bf16 bf16x8;
typedef __attribute__((ext_vector_type(4))) float floatx4;
typedef __attribute__((ext_vector_type(2))) unsigned int uintx2;

// fp32 -> bf16 round-to-nearest-even (finite inputs)
__device__ __forceinline__ unsigned int f2bf(float f) {
    unsigned int u = __builtin_bit_cast(unsigned int, f);
    u += 0x7fffu + ((u >> 16) & 1u);
    return u >> 16;
}

// ------------- fused prep: W dequant-gather + x fp32->bf16 -------------
__global__ __launch_bounds__(256) void prep_kernel(
    const float* __restrict__ cb, const int* __restrict__ idx,
    uint4* __restrict__ W, const floatx4* __restrict__ x,
    uintx2* __restrict__ xb) {
    const int wg = blockIdx.x;
    if (wg < W_WGS) {
        const int b = wg * 256 + threadIdx.x;
        const int id = __builtin_nontemporal_load(idx + b);
        const float4* s = (const float4*)(cb + ((size_t)id << 3));
        const float4 a = s[0];
        const float4 c = s[1];
        uint4 o;
        o.x = f2bf(a.x) | (f2bf(a.y) << 16);
        o.y = f2bf(a.z) | (f2bf(a.w) << 16);
        o.z = f2bf(c.x) | (f2bf(c.y) << 16);
        o.w = f2bf(c.z) | (f2bf(c.w) << 16);
        W[b] = o;
    } else {
        const size_t t = (size_t)(wg - W_WGS) * 256 + threadIdx.x;
        const floatx4 a = __builtin_nontemporal_load(x + t);
        uintx2 o;
        o.x = f2bf(a.x) | (f2bf(a.y) << 16);
        o.y = f2bf(a.z) | (f2bf(a.w) << 16);
        xb[t] = o;
    }
}

// ---------------- async global -> LDS, 16B per lane ----------------
__device__ __forceinline__ void async_copy16(const __bf16* g, __bf16* s) {
    __builtin_amdgcn_global_load_lds(
        (const __attribute__((address_space(1))) unsigned int*)(uintptr_t)g,
        (__attribute__((address_space(3))) unsigned int*)(uintptr_t)s,
        16, 0, 0);
}

// Stage one unit = one operand k-half (256 rows x 32 bf16 = 16 KiB):
// 2 global_load_lds per thread (rows 0-127, rows 128-255).
#define STAGE(gsrc, arr, slotElems)                                        \
    do {                                                                   \
        async_copy16((gsrc), (arr) + (slotElems) + wave512);               \
        async_copy16((gsrc) + (size_t)128 * K_DIM,                         \
                     (arr) + (slotElems) + 4096 + wave512);                \
    } while (0)

// ---------------- GEMM: C[M][N] = A[M][K] * B[N][K]^T + bias ----------------
// 512 threads = 8 waves (2M x 4N); wave owns 128x64 output = acc[8][4] f32x4.
// LDS: per operand a 4-slot ring of 16KiB k-half units: slot = (t&1)*2 + kh.
// 2 phases per K-tile. Register sets: (fA0,fB0) and (fA1,fB1) ping-pong the
// phase-entry fragments; fC carries the in-phase af1.
//   Phase A (kh0): [STAGE kh1(t+1)] [fC<-af1 kh0][fB1<-bfr kh1][fA1<-af0 kh1]
//                  [sched_barrier(0)] [half0: fA0xfB0] [half1: fCxfB0]
//                  [vmcnt(4)] [barrier]
//   Phase B (kh1): symmetric, prereads kh0(t+1) into fA0/fB0.
// Fences identical to R10/R11: every phase ends vmcnt(4); tails 0.
__global__ __launch_bounds__(512, 2) void gemm_bt_kernel(
    const __bf16* __restrict__ A,   // [M][K] bf16
    const __bf16* __restrict__ B,   // [N][K] bf16
    const float* __restrict__ bias, // [N]
    float* __restrict__ C) {        // [M][N] fp32
    __shared__ __align__(16) __bf16 sA[4 * 8192];   // 64 KiB
    __shared__ __align__(16) __bf16 sB[4 * 8192];   // 64 KiB

    const int tid = threadIdx.x;
    const int wave = tid >> 6;
    const int lane = tid & 63;
    const int wr = wave >> 2;            // 0..1  (M half of tile)
    const int wc = wave & 3;             // 0..3  (N quarter of tile)

    // T1: XCD-chunked mapping (verified R6: FETCH 670->197 MB).
    const int flat = blockIdx.x;
    const int xcd = flat & 7;
    const int q = flat >> 3;             // 0..63
    const int half = q >> 5;             // 0..1
    const int sq = q & 31;
    const int m0 = ((xcd & 3) * 8 + half * 4 + (sq & 3)) * BM;
    const int n0 = ((xcd >> 2) * 8 + (sq >> 2)) * BN;

    // staging: thread t covers row = t>>2 (+128 for 2nd half), phys chunk t&3;
    // fetch logical chunk c = p ^ ((row>>1)&3) (involution, invariant +16/+128)
    const int srow = tid >> 2;
    const int schunk = ((tid & 3) ^ ((srow >> 1) & 3)) << 3;
    const __bf16* gA = A + (size_t)(m0 + srow) * K_DIM + schunk;
    const __bf16* gB = B + (size_t)(n0 + srow) * K_DIM + schunk;
    const int wave512 = wave << 9;

    // fragment reads: lane holds X[row = base + fr][k = (lane>>4)*8 + j];
    // physical chunk = (lane>>4) ^ ((fr>>1)&3).
    const int fr = lane & 15;
    const int roff = fr * 32 + (((lane >> 4) ^ ((fr >> 1) & 3)) << 3);
    const int aBase = wr * 4096 + roff;  // wr*128 rows * 32 elems
    const int bBase = wc * 2048 + roff;  // wc*64 rows * 32 elems

    floatx4 acc[8][4] = {};
    bf16x8 fA0[4], fB0[4], fA1[4], fB1[4], fC[4];

    // ---- prologue: kh0(0), kh1(0), kh0(1) staged in FIFO order ----
    STAGE(gA, sA, 0);             // A kh0 t0 -> slot 0
    STAGE(gB, sB, 0);
    STAGE(gA + 32, sA, 8192);     // A kh1 t0 -> slot 1
    STAGE(gB + 32, sB, 8192);
    STAGE(gA + 64, sA, 16384);    // A kh0 t1 -> slot 2
    STAGE(gB + 64, sB, 16384);
    // drain kh0(0)+kh1(0) (8 of 12); kh0(1) stays in flight
    asm volatile("s_waitcnt vmcnt(4)" ::: "memory");
    __builtin_amdgcn_s_barrier();
    // preload entry fragments for phase A(0): af0/bfr of kh0(0)
#pragma unroll
    for (int i = 0; i < 4; ++i)
        fA0[i] = *(const bf16x8*)(sA + aBase + i * 512);
#pragma unroll
    for (int j = 0; j < 4; ++j)
        fB0[j] = *(const bf16x8*)(sB + bBase + j * 512);

    for (int t = 0; t < NT; ++t) {
        const int cs = (t & 1) ? 16384 : 0;   // this tile's kh0 slot (elems)
        const int ns = cs ^ 16384;            // next tile's kh0 slot
        const __bf16* pA0 = sA + cs;          // kh0(t)
        const __bf16* pA1 = sA + cs + 8192;   // kh1(t)
        const __bf16* pB1 = sB + cs + 8192;
        const __bf16* nA0 = sA + ns;          // kh0(t+1)
        const __bf16* nB0 = sB + ns;

        // ===== Phase A: compute kh0(t) [fA0,fB0]; preread kh1(t) =====
        if (t + 1 < NT) {
            STAGE(gA + (size_t)(t + 1) * 64 + 32, sA, ns + 8192);
            STAGE(gB + (size_t)(t + 1) * 64 + 32, sB, ns + 8192);
        }
#pragma unroll
        for (int i = 0; i < 4; ++i)           // af1(kh0): used by half1
            fC[i] = *(const bf16x8*)(pA0 + aBase + 2048 + i * 512);
#pragma unroll
        for (int j = 0; j < 4; ++j)           // bfr(kh1): next phase
            fB1[j] = *(const bf16x8*)(pB1 + bBase + j * 512);
#pragma unroll
        for (int i = 0; i < 4; ++i)           // af0(kh1): next phase
            fA1[i] = *(const bf16x8*)(pA1 + aBase + i * 512);
        // pin: all 12 ds_reads issued BEFORE the MFMA cluster
        __builtin_amdgcn_sched_barrier(0);
        __builtin_amdgcn_s_setprio(1);
#pragma unroll
        for (int i = 0; i < 4; ++i)
#pragma unroll
            for (int j = 0; j < 4; ++j)
                acc[i][j] = __builtin_amdgcn_mfma_f32_16x16x32_bf16(
                    fA0[i], fB0[j], acc[i][j], 0, 0, 0);
#pragma unroll
        for (int i = 0; i < 4; ++i)
#pragma unroll
            for (int j = 0; j < 4; ++j)
                acc[i + 4][j] = __builtin_amdgcn_mfma_f32_16x16x32_bf16(
                    fC[i], fB0[j], acc[i + 4][j], 0, 0, 0);
        __builtin_amdgcn_s_setprio(0);
        // publish kh0(t+1): outstanding [kh0(t+1)4, kh1(t+1)4] -> 4
        if (t + 1 < NT)
            asm volatile("s_waitcnt vmcnt(4)" ::: "memory");
        else
            asm volatile("s_waitcnt vmcnt(0)" ::: "memory");
        __builtin_amdgcn_s_barrier();

        // ===== Phase B: compute kh1(t) [fA1,fB1]; preread kh0(t+1) =====
        if (t + 2 < NT) {
            STAGE(gA + (size_t)(t + 2) * 64, sA, cs);
            STAGE(gB + (size_t)(t + 2) * 64, sB, cs);
        }
#pragma unroll
        for (int i = 0; i < 4; ++i)           // af1(kh1): used by half1
            fC[i] = *(const bf16x8*)(pA1 + aBase + 2048 + i * 512);
        if (t + 1 < NT) {
#pragma unroll
            for (int j = 0; j < 4; ++j)       // bfr(kh0,t+1): next phase
                fB0[j] = *(const bf16x8*)(nB0 + bBase + j * 512);
#pragma unroll
            for (int i = 0; i < 4; ++i)       // af0(kh0,t+1): next phase
                fA0[i] = *(const bf16x8*)(nA0 + aBase + i * 512);
        }
        // pin: all ds_reads issued BEFORE the MFMA cluster
        __builtin_amdgcn_sched_barrier(0);
        __builtin_amdgcn_s_setprio(1);
#pragma unroll
        for (int i = 0; i < 4; ++i)
#pragma unroll
            for (int j = 0; j < 4; ++j)
                acc[i][j] = __builtin_amdgcn_mfma_f32_16x16x32_bf16(
                    fA1[i], fB1[j], acc[i][j], 0, 0, 0);
#pragma unroll
        for (int i = 0; i < 4; ++i)
#pragma unroll
            for (int j = 0; j < 4; ++j)
                acc[i + 4][j] = __builtin_amdgcn_mfma_f32_16x16x32_bf16(
                    fC[i], fB1[j], acc[i + 4][j], 0, 0, 0);
        __builtin_amdgcn_s_setprio(0);
        // publish kh1(t+1): outstanding [kh1(t+1)4, kh0(t+2)4] -> 4
        if (t + 2 < NT)
            asm volatile("s_waitcnt vmcnt(4)" ::: "memory");
        else
            asm volatile("s_waitcnt vmcnt(0)" ::: "memory");
        __builtin_amdgcn_s_barrier();
    }

    // Epilogue. C/D layout: col = lane&15, row = (lane>>4)*4 + reg
    const int crow = (lane >> 4) * 4;
    const int ccol = lane & 15;
#pragma unroll
    for (int j = 0; j < 4; ++j) {
        const int n = n0 + wc * 64 + j * 16 + ccol;
        const float bv = bias[n];
#pragma unroll
        for (int i = 0; i < 8; ++i) {
            const int m = m0 + wr * 128 + i * 16 + crow;
            float* cp = C + (size_t)m * N_DIM + n;
#pragma unroll
            for (int r = 0; r < 4; ++r)
                __builtin_nontemporal_store(acc[i][j][r] + bv,
                                            cp + (size_t)r * N_DIM);
        }
    }
}

extern "C" void kernel_launch(void* const* d_in, const int* in_sizes, int n_in,
                              void* d_out, int out_size, void* d_ws, size_t ws_size,
                              hipStream_t stream) {
    const float* x    = (const float*)d_in[0];   // [4,2048,4096] fp32
    const float* cb   = (const float*)d_in[1];   // [4096,8] fp32
    const int*   idx  = (const int*)d_in[2];     // [2M]
    const float* bias = (const float*)d_in[3];   // [4096]
    float* out = (float*)d_out;                  // [4,2048,4096] fp32

    // workspace layout: W_bf16 (32 MB) | x_bf16 (64 MB)
    __bf16* Wb = (__bf16*)d_ws;
    __bf16* Xb = (__bf16*)((char*)d_ws + (size_t)N_DIM * K_DIM * sizeof(__bf16));

    prep_kernel<<<W_WGS + X_WGS, 256, 0, stream>>>(
        cb, idx, (uint4*)Wb, (const floatx4*)x, (uintx2*)Xb);

    dim3 grid(M_DIM / BM * (N_DIM / BN));  // 512 WGs, XCD-chunked in-kernel
    gemm_bt_kernel<<<grid, 512, 0, stream>>>(Xb, Wb, bias, out);
}